// Round 1
// baseline (397.099 us; speedup 1.0000x reference)
//
#include <hip/hip_runtime.h>

// LearnedSegmentEncoder on MI355X.
// B=8, C=128, H=W=256 (P=65536), D=64, S=32.
// Math identity used: pooled = conv2_w @ mean_seg(relu(conv1_w@x+b1)) + b2
// (conv2 is linear, hoisted past the segment mean), so only conv1 runs per-pixel.

#define B_ 8
#define C_ 128
#define P_ 65536
#define D_ 64
#define S_ 32
#define PB 128            // blocks per batch
#define TPB 256           // threads per block
#define PIX_PER_BLOCK (P_ / PB)   // 512 = 2 pixels per thread

__global__ __launch_bounds__(TPB) void seg_proj_scatter(
    const int* __restrict__ labels, const float* __restrict__ feat,
    const float* __restrict__ w1, const float* __restrict__ b1,
    float* __restrict__ gsum, int* __restrict__ gcnt)
{
  // W1 staged as [c][d] so each c-iteration reads d-contiguous float4s (broadcast).
  __shared__ __align__(16) float w_lds[C_ * D_];       // 32 KB
  __shared__ float s_acc[S_ * 65];                     // pad 65: bank=(label+d)%32
  __shared__ int   s_cnt[S_];
  __shared__ float b_lds[D_];

  const int tid = threadIdx.x;
  const int b = blockIdx.y;
  const int p0 = blockIdx.x * PIX_PER_BLOCK;

  for (int i = tid; i < C_ * D_; i += TPB) {
    int d = i >> 7, c = i & (C_ - 1);                  // w1 is (D=64, C=128) row-major
    w_lds[c * D_ + d] = w1[i];
  }
  for (int i = tid; i < S_ * 65; i += TPB) s_acc[i] = 0.f;
  if (tid < S_) s_cnt[tid] = 0;
  if (tid < D_) b_lds[tid] = b1[tid];
  __syncthreads();

  const int pix = p0 + tid;                            // second pixel = pix + TPB
  const float* xp = feat + (size_t)b * C_ * P_ + pix;

  float acc0[D_], acc1[D_];
  #pragma unroll
  for (int d = 0; d < D_; ++d) { acc0[d] = 0.f; acc1[d] = 0.f; }

  #pragma unroll 4
  for (int c = 0; c < C_; ++c) {
    float x0 = xp[(size_t)c * P_];                     // coalesced across lanes
    float x1 = xp[(size_t)c * P_ + TPB];
    const float4* w4 = (const float4*)&w_lds[c * D_];
    #pragma unroll
    for (int q = 0; q < D_ / 4; ++q) {
      float4 w = w4[q];
      acc0[4*q+0] += w.x * x0; acc0[4*q+1] += w.y * x0;
      acc0[4*q+2] += w.z * x0; acc0[4*q+3] += w.w * x0;
      acc1[4*q+0] += w.x * x1; acc1[4*q+1] += w.y * x1;
      acc1[4*q+2] += w.z * x1; acc1[4*q+3] += w.w * x1;
    }
  }

  const int l0 = labels[(size_t)b * P_ + pix] & (S_ - 1);
  const int l1 = labels[(size_t)b * P_ + pix + TPB] & (S_ - 1);
  atomicAdd(&s_cnt[l0], 1);
  atomicAdd(&s_cnt[l1], 1);
  const int r0 = l0 * 65, r1 = l1 * 65;
  #pragma unroll
  for (int d = 0; d < D_; ++d)
    atomicAdd(&s_acc[r0 + d], fmaxf(acc0[d] + b_lds[d], 0.f));
  #pragma unroll
  for (int d = 0; d < D_; ++d)
    atomicAdd(&s_acc[r1 + d], fmaxf(acc1[d] + b_lds[d], 0.f));

  __syncthreads();
  for (int i = tid; i < S_ * D_; i += TPB) {
    int s = i >> 6, d = i & 63;
    atomicAdd(&gsum[((size_t)b * S_ + s) * D_ + d], s_acc[s * 65 + d]);
  }
  if (tid < S_) atomicAdd(&gcnt[b * S_ + tid], s_cnt[tid]);
}

// One block per batch, 64 lanes (= one wave, lane o = output channel).
__global__ __launch_bounds__(64) void seg_finalize(
    const float* __restrict__ gsum, const int* __restrict__ gcnt,
    const float* __restrict__ w2, const float* __restrict__ b2,
    const float* __restrict__ emb, const float* __restrict__ wo,
    const float* __restrict__ bo, float* __restrict__ out)
{
  const int b = blockIdx.x, o = threadIdx.x;
  __shared__ float s_mean[D_], s_pool[D_];
  int rank = 0;
  for (int s = 0; s < S_; ++s) {
    const int cnt = gcnt[b * S_ + s];                  // uniform across lanes
    const float inv = 1.f / (float)max(cnt, 1);
    s_mean[o] = gsum[((size_t)b * S_ + s) * D_ + o] * inv;
    __syncthreads();
    float pooled = b2[o];
    #pragma unroll
    for (int d = 0; d < D_; ++d) pooled += w2[o * D_ + d] * s_mean[d];
    s_pool[o] = pooled;
    __syncthreads();
    float r = bo[o];
    #pragma unroll
    for (int e = 0; e < D_; ++e) r += wo[o * 2 * D_ + e] * s_pool[e];
    #pragma unroll
    for (int e = 0; e < D_; ++e) r += wo[o * 2 * D_ + D_ + e] * emb[s * D_ + e];
    if (cnt > 0) {                                     // uniform branch
      out[((size_t)b * S_ + rank) * D_ + o] = r;
      rank++;
    }
    __syncthreads();                                   // protect s_mean/s_pool reuse
  }
}

extern "C" void kernel_launch(void* const* d_in, const int* in_sizes, int n_in,
                              void* d_out, int out_size, void* d_ws, size_t ws_size,
                              hipStream_t stream) {
  const int*   labels = (const int*)  d_in[0];
  const float* feat   = (const float*)d_in[1];
  const float* w1     = (const float*)d_in[2];
  const float* b1     = (const float*)d_in[3];
  const float* w2     = (const float*)d_in[4];
  const float* b2     = (const float*)d_in[5];
  const float* emb    = (const float*)d_in[6];
  const float* wo     = (const float*)d_in[7];
  const float* bo     = (const float*)d_in[8];
  float* out = (float*)d_out;

  float* gsum = (float*)d_ws;                               // B*S*D floats
  int*   gcnt = (int*)((char*)d_ws + (size_t)B_ * S_ * D_ * sizeof(float));
  const size_t zbytes = (size_t)B_ * S_ * D_ * sizeof(float)
                      + (size_t)B_ * S_ * sizeof(int);
  hipMemsetAsync(d_ws, 0, zbytes, stream);
  hipMemsetAsync(d_out, 0, (size_t)out_size * sizeof(float), stream);

  dim3 grid(PB, B_);
  seg_proj_scatter<<<grid, TPB, 0, stream>>>(labels, feat, w1, b1, gsum, gcnt);
  seg_finalize<<<B_, 64, 0, stream>>>(gsum, gcnt, w2, b2, emb, wo, bo, out);
}

// Round 2
// 290.295 us; speedup vs baseline: 1.3679x; 1.3679x over previous
//
#include <hip/hip_runtime.h>

// LearnedSegmentEncoder on MI355X — MFMA version.
// B=8, C=128, P=65536, D=64, S=32.
// Identity: pooled = conv2_w @ mean_seg(relu(conv1_w@x+b1)) + b2 (conv2 hoisted
// past the segment mean), so only conv1 runs per-pixel — as a bf16 MFMA GEMM
// with A-fragments loaded straight from global (coalesced, no LDS staging).

#define B_ 8
#define C_ 128
#define P_ 65536
#define D_ 64
#define S_ 32

typedef short  bf16x8 __attribute__((ext_vector_type(8)));
typedef float  f32x4  __attribute__((ext_vector_type(4)));

__device__ __forceinline__ short f2bf(float f) {
  union { float f; unsigned u; } v; v.f = f;
  unsigned r = v.u + 0x7fffu + ((v.u >> 16) & 1u);   // RNE
  return (short)(r >> 16);
}

__global__ __launch_bounds__(256) void w1_to_bf16(const float* __restrict__ w1,
                                                  short* __restrict__ wbf) {
  int i = blockIdx.x * 256 + threadIdx.x;
  if (i < C_ * D_) wbf[i] = f2bf(w1[i]);
}

// 256 thr = 4 waves; each wave does 8 pixel-tiles of 16 -> 512 pixels/block.
// Grid (P/512, B).
__global__ __launch_bounds__(256, 2) void proj_mfma(
    const int* __restrict__ labels, const float* __restrict__ feat,
    const short* __restrict__ wbf, const float* __restrict__ b1,
    float* __restrict__ gsum, int* __restrict__ gcnt)
{
  __shared__ float s_acc[S_][68];   // bank = (4*lab + d) % 32 — spreads labels
  __shared__ int   s_cnt[S_];

  const int tid  = threadIdx.x;
  const int wave = tid >> 6, l = tid & 63, m = l & 15, g = l >> 4;
  const int b     = blockIdx.y;
  const int pbase = blockIdx.x * 512;

  for (int i = tid; i < S_ * 68; i += 256) ((float*)s_acc)[i] = 0.f;
  if (tid < S_) s_cnt[tid] = 0;

  // B-fragments (W1 as K x N = w1^T): lane l, tile nt, kstep ks needs
  // w1[d = nt*16+m][c = ks*32 + g*8 + j], j=0..7 — 16B contiguous.
  bf16x8 bfr[4][4];
  #pragma unroll
  for (int nt = 0; nt < 4; ++nt)
    #pragma unroll
    for (int ks = 0; ks < 4; ++ks)
      bfr[nt][ks] = *(const bf16x8*)&wbf[(nt * 16 + m) * C_ + ks * 32 + g * 8];

  float b1v[4];
  #pragma unroll
  for (int nt = 0; nt < 4; ++nt) b1v[nt] = b1[nt * 16 + m];

  __syncthreads();

  const float* xb = feat   + (size_t)b * C_ * P_;
  const int*   lb = labels + (size_t)b * P_;

  for (int t = 0; t < 8; ++t) {
    const int p0 = pbase + (wave + 4 * t) * 16;

    // labels for output rows: row = g*4 + r  -> pixel p0 + g*4 + r
    const int4 labv = *(const int4*)&lb[p0 + g * 4];

    // A-fragments direct from global: lane reads x[c = ks*32+g*8+j][p0+m].
    // Per (ks,j) instr: 4 groups x 16 consecutive pixels = 4x64B segments.
    const float* xp = xb + (size_t)(g * 8) * P_ + p0 + m;
    float xv[4][8];
    #pragma unroll
    for (int ks = 0; ks < 4; ++ks)
      #pragma unroll
      for (int j = 0; j < 8; ++j)
        xv[ks][j] = xp[(size_t)(ks * 32 + j) * P_];

    bf16x8 af[4];
    #pragma unroll
    for (int ks = 0; ks < 4; ++ks)
      #pragma unroll
      for (int j = 0; j < 8; ++j)
        af[ks][j] = f2bf(xv[ks][j]);

    f32x4 acc[4] = {{0,0,0,0},{0,0,0,0},{0,0,0,0},{0,0,0,0}};
    #pragma unroll
    for (int nt = 0; nt < 4; ++nt)
      #pragma unroll
      for (int ks = 0; ks < 4; ++ks)
        acc[nt] = __builtin_amdgcn_mfma_f32_16x16x32_bf16(af[ks], bfr[nt][ks],
                                                          acc[nt], 0, 0, 0);

    // C/D layout: d = nt*16 + (lane&15), pixel-row = g*4 + r  (verified m89).
    #pragma unroll
    for (int nt = 0; nt < 4; ++nt) {
      #pragma unroll
      for (int r = 0; r < 4; ++r) {
        const int lab = (r & 2) ? ((r & 1) ? labv.w : labv.z)
                                : ((r & 1) ? labv.y : labv.x);
        const float v = fmaxf(acc[nt][r] + b1v[nt], 0.f);
        atomicAdd(&s_acc[lab & (S_ - 1)][nt * 16 + m], v);
      }
    }
    // counts: lanes (l&15)<4 cover the tile's 16 pixels in one instr
    if (m < 4) {
      const int lab = (m & 2) ? ((m & 1) ? labv.w : labv.z)
                              : ((m & 1) ? labv.y : labv.x);
      atomicAdd(&s_cnt[lab & (S_ - 1)], 1);
    }
  }

  __syncthreads();
  for (int i = tid; i < S_ * D_; i += 256) {
    int s = i >> 6, d = i & 63;
    atomicAdd(&gsum[((size_t)b * S_ + s) * D_ + d], s_acc[s][d]);
  }
  if (tid < S_) atomicAdd(&gcnt[b * S_ + tid], s_cnt[tid]);
}

// One block per batch, 64 lanes (one wave, lane o = output channel).
__global__ __launch_bounds__(64) void seg_finalize(
    const float* __restrict__ gsum, const int* __restrict__ gcnt,
    const float* __restrict__ w2, const float* __restrict__ b2,
    const float* __restrict__ emb, const float* __restrict__ wo,
    const float* __restrict__ bo, float* __restrict__ out)
{
  const int b = blockIdx.x, o = threadIdx.x;
  __shared__ float s_mean[D_], s_pool[D_];
  int rank = 0;
  for (int s = 0; s < S_; ++s) {
    const int cnt = gcnt[b * S_ + s];                  // uniform across lanes
    const float inv = 1.f / (float)max(cnt, 1);
    s_mean[o] = gsum[((size_t)b * S_ + s) * D_ + o] * inv;
    __syncthreads();
    float pooled = b2[o];
    #pragma unroll
    for (int d = 0; d < D_; ++d) pooled += w2[o * D_ + d] * s_mean[d];
    s_pool[o] = pooled;
    __syncthreads();
    float r = bo[o];
    #pragma unroll
    for (int e = 0; e < D_; ++e) r += wo[o * 2 * D_ + e] * s_pool[e];
    #pragma unroll
    for (int e = 0; e < D_; ++e) r += wo[o * 2 * D_ + D_ + e] * emb[s * D_ + e];
    if (cnt > 0) {                                     // uniform branch
      out[((size_t)b * S_ + rank) * D_ + o] = r;
      rank++;
    }
    __syncthreads();
  }
}

extern "C" void kernel_launch(void* const* d_in, const int* in_sizes, int n_in,
                              void* d_out, int out_size, void* d_ws, size_t ws_size,
                              hipStream_t stream) {
  const int*   labels = (const int*)  d_in[0];
  const float* feat   = (const float*)d_in[1];
  const float* w1     = (const float*)d_in[2];
  const float* b1     = (const float*)d_in[3];
  const float* w2     = (const float*)d_in[4];
  const float* b2     = (const float*)d_in[5];
  const float* emb    = (const float*)d_in[6];
  const float* wo     = (const float*)d_in[7];
  const float* bo     = (const float*)d_in[8];
  float* out = (float*)d_out;

  float* gsum = (float*)d_ws;                                  // B*S*D f32
  int*   gcnt = (int*)((char*)d_ws + (size_t)B_*S_*D_*4);      // B*S i32
  short* wbf  = (short*)((char*)d_ws + (size_t)B_*S_*D_*4 + (size_t)B_*S_*4);

  const size_t zbytes = (size_t)B_*S_*D_*4 + (size_t)B_*S_*4;
  hipMemsetAsync(d_ws, 0, zbytes, stream);
  hipMemsetAsync(d_out, 0, (size_t)out_size * sizeof(float), stream);

  w1_to_bf16<<<(C_*D_ + 255)/256, 256, 0, stream>>>(w1, wbf);

  dim3 grid(P_ / 512, B_);
  proj_mfma<<<grid, 256, 0, stream>>>(labels, feat, wbf, b1, gsum, gcnt);
  seg_finalize<<<B_, 64, 0, stream>>>(gsum, gcnt, w2, b2, emb, wo, bo, out);
}